// Round 3
// baseline (130.670 us; speedup 1.0000x reference)
//
#include <hip/hip_runtime.h>
#include <math.h>

#define BB 8
#define TT 4096
#define DD 2048
#define THREADS 256            // 4 waves; D/THREADS = 8 floats/thread
#define NWAVES (THREADS / 64)

typedef float v4f __attribute__((ext_vector_type(4)));

__device__ __forceinline__ float fast_tanh(float a) {
    // tanh(a) = 1 - 2/(exp(2a)+1); __expf -> v_exp_f32, saturates cleanly.
    float e = __expf(2.0f * a);
    return 1.0f - 2.0f / (e + 1.0f);
}

__device__ __forceinline__ float gelu_tanh(float x) {
    const float c = 0.7978845608028654f;  // sqrt(2/pi)
    float inner = c * (x + 0.044715f * x * x * x);
    return 0.5f * x * (1.0f + fast_tanh(inner));
}

__device__ __forceinline__ void gelu4_dot(v4f& v, const v4f& p,
                                          float& d, float& n) {
    v.x = gelu_tanh(v.x); v.y = gelu_tanh(v.y);
    v.z = gelu_tanh(v.z); v.w = gelu_tanh(v.w);
    d += v.x * p.x + v.y * p.y + v.z * p.z + v.w * p.w;
    n += v.x * v.x + v.y * v.y + v.z * v.z + v.w * v.w;
}

__global__ __launch_bounds__(THREADS, 4) void gelu275_fused(
    const float* __restrict__ x,          // [B,T,D]
    const float* __restrict__ log_k_pos,  // [1]
    const float* __restrict__ pos_buf,    // [T,D]
    const float* __restrict__ pos_facil,  // [T]
    float* __restrict__ out)              // [B,T,D]
{
    const int t    = blockIdx.x;
    const int tid  = threadIdx.x;
    const int lane = tid & 63;
    const int wave = tid >> 6;

    __shared__ float red[NWAVES][17];   // per-wave partials: pn2 + dot[8] + yn2[8]

    const size_t col = (size_t)tid * 8;

    // ---- Phase 1: issue ALL loads back-to-back (18 x float4 in flight) ----
    v4f xa[BB], xb[BB];
#pragma unroll
    for (int b = 0; b < BB; ++b) {
        const float* px = x + ((size_t)b * TT + t) * DD + col;
        xa[b] = *reinterpret_cast<const v4f*>(px);
        xb[b] = *reinterpret_cast<const v4f*>(px + 4);
    }
    const float* pp = pos_buf + (size_t)t * DD + col;
    const v4f pa = *reinterpret_cast<const v4f*>(pp);
    const v4f pb = *reinterpret_cast<const v4f*>(pp + 4);

    float pn2 = pa.x*pa.x + pa.y*pa.y + pa.z*pa.z + pa.w*pa.w
              + pb.x*pb.x + pb.y*pb.y + pb.z*pb.z + pb.w*pb.w;

    // ---- Phase 2: gelu in-place + per-row partial dot / norm ----
    float dotp[BB], yn2[BB];
#pragma unroll
    for (int b = 0; b < BB; ++b) {
        float d = 0.0f, n = 0.0f;
        gelu4_dot(xa[b], pa, d, n);
        gelu4_dot(xb[b], pb, d, n);
        dotp[b] = d;
        yn2[b]  = n;
    }

    // ---- Phase 3: wave butterfly reduction of 17 partials ----
#pragma unroll
    for (int off = 32; off; off >>= 1) {
        pn2 += __shfl_xor(pn2, off);
#pragma unroll
        for (int b = 0; b < BB; ++b) {
            dotp[b] += __shfl_xor(dotp[b], off);
            yn2[b]  += __shfl_xor(yn2[b],  off);
        }
    }
    if (lane == 0) {
        red[wave][0] = pn2;
#pragma unroll
        for (int b = 0; b < BB; ++b) {
            red[wave][1 + b] = dotp[b];
            red[wave][9 + b] = yn2[b];
        }
    }
    __syncthreads();

    // ---- Phase 4: lane (l&7) of each 8-lane group computes gate[l&7] ----
    const int myb = lane & 7;
    float P = 0.0f, Dt = 0.0f, Yn = 0.0f;
#pragma unroll
    for (int w = 0; w < NWAVES; ++w) {
        P  += red[w][0];
        Dt += red[w][1 + myb];
        Yn += red[w][9 + myb];
    }
    const float kp = fminf(fmaxf(__expf(log_k_pos[0]), 0.01f), 5.0f);
    const float pn = fmaxf(sqrtf(P),  1e-12f);
    const float yn = fmaxf(sqrtf(Yn), 1e-12f);
    const float sim = Dt / (yn * pn);

    // mean over b: 3-round xor reduce within each 8-lane group
    float simsum = sim;
    simsum += __shfl_xor(simsum, 1);
    simsum += __shfl_xor(simsum, 2);
    simsum += __shfl_xor(simsum, 4);

    const bool  fire  = (simsum * (1.0f / BB)) > 0.85f;
    const float pf    = pos_facil[t];
    const float facil = fire ? fminf(pf * 2.0f, 16.0f) : pf;
    const float myg   = fminf(1.0f + kp * (facil - 1.0f) * sim, 8.0f);

    // ---- Phase 5: gated write-out (nontemporal float4) ----
#pragma unroll
    for (int b = 0; b < BB; ++b) {
        const float g = __shfl(myg, b, 8);
        float* po = out + ((size_t)b * TT + t) * DD + col;
        v4f o0, o1;
        o0.x = xa[b].x * g; o0.y = xa[b].y * g;
        o0.z = xa[b].z * g; o0.w = xa[b].w * g;
        o1.x = xb[b].x * g; o1.y = xb[b].y * g;
        o1.z = xb[b].z * g; o1.w = xb[b].w * g;
        __builtin_nontemporal_store(o0, reinterpret_cast<v4f*>(po));
        __builtin_nontemporal_store(o1, reinterpret_cast<v4f*>(po + 4));
    }
}

extern "C" void kernel_launch(void* const* d_in, const int* in_sizes, int n_in,
                              void* d_out, int out_size, void* d_ws, size_t ws_size,
                              hipStream_t stream) {
    const float* x          = (const float*)d_in[0];
    const float* log_k_pos  = (const float*)d_in[1];
    const float* pos_buf    = (const float*)d_in[2];
    const float* pos_facil  = (const float*)d_in[3];
    float* out              = (float*)d_out;

    dim3 grid(TT);
    dim3 block(THREADS);
    gelu275_fused<<<grid, block, 0, stream>>>(x, log_k_pos, pos_buf, pos_facil, out);
}

// Round 4
// 126.604 us; speedup vs baseline: 1.0321x; 1.0321x over previous
//
#include <hip/hip_runtime.h>
#include <math.h>

#define BB 8
#define TT 4096
#define DD 2048
#define THREADS 512           // 8 waves; wave w owns batch row b=w
#define CHUNKS 8              // DD / (64 lanes * 4 floats) = 8 chunks/lane

typedef float v4f __attribute__((ext_vector_type(4)));

__device__ __forceinline__ float fast_tanh(float a) {
    // tanh(a) = 1 - 2/(exp(2a)+1); __expf -> v_exp_f32, saturates cleanly.
    float e = __expf(2.0f * a);
    return 1.0f - 2.0f / (e + 1.0f);
}

__device__ __forceinline__ float gelu_tanh(float x) {
    const float c = 0.7978845608028654f;  // sqrt(2/pi)
    float inner = c * (x + 0.044715f * x * x * x);
    return 0.5f * x * (1.0f + fast_tanh(inner));
}

__global__ __launch_bounds__(THREADS) void gelu275_fused(
    const float* __restrict__ x,          // [B,T,D]
    const float* __restrict__ log_k_pos,  // [1]
    const float* __restrict__ pos_buf,    // [T,D]
    const float* __restrict__ pos_facil,  // [T]
    float* __restrict__ out)              // [B,T,D]
{
    const int t    = blockIdx.x;
    const int tid  = threadIdx.x;
    const int lane = tid & 63;
    const int wave = tid >> 6;            // == batch row b for this wave

    __shared__ float s_dot[BB];
    __shared__ float s_yn2[BB];
    __shared__ float s_pn2;

    const float* xrow = x       + ((size_t)wave * TT + t) * DD;
    const float* prow = pos_buf + (size_t)t * DD;
    const int    base = lane * 4;

    // ---- Phase 1: issue all 16 loads back-to-back (true 16-deep MLP) ----
    v4f xv[CHUNKS], pv[CHUNKS];
#pragma unroll
    for (int c = 0; c < CHUNKS; ++c)
        xv[c] = *reinterpret_cast<const v4f*>(xrow + c * 256 + base);
#pragma unroll
    for (int c = 0; c < CHUNKS; ++c)
        pv[c] = *reinterpret_cast<const v4f*>(prow + c * 256 + base);

    // ---- Phase 2: gelu in-place + partial dot / norms ----
    float dot = 0.0f, yn2 = 0.0f, pn2 = 0.0f;
#pragma unroll
    for (int c = 0; c < CHUNKS; ++c) {
        v4f& v = xv[c];
        const v4f& p = pv[c];
        v.x = gelu_tanh(v.x); v.y = gelu_tanh(v.y);
        v.z = gelu_tanh(v.z); v.w = gelu_tanh(v.w);
        dot += v.x * p.x + v.y * p.y + v.z * p.z + v.w * p.w;
        yn2 += v.x * v.x + v.y * v.y + v.z * v.z + v.w * v.w;
        pn2 += p.x * p.x + p.y * p.y + p.z * p.z + p.w * p.w;
    }

    // ---- Phase 3: wave butterfly (3 values x 6 rounds = 18 shfl) ----
#pragma unroll
    for (int off = 32; off; off >>= 1) {
        dot += __shfl_xor(dot, off);
        yn2 += __shfl_xor(yn2, off);
        pn2 += __shfl_xor(pn2, off);
    }
    if (lane == 0) {
        s_dot[wave] = dot;
        s_yn2[wave] = yn2;
        if (wave == 0) s_pn2 = pn2;
    }
    __syncthreads();

    // ---- Phase 4: every thread computes gates from the 17 LDS scalars ----
    const float kp = fminf(fmaxf(__expf(log_k_pos[0]), 0.01f), 5.0f);
    const float pn = fmaxf(sqrtf(s_pn2), 1e-12f);

    float simsum = 0.0f;
    float simw   = 0.0f;
#pragma unroll
    for (int b = 0; b < BB; ++b) {
        const float s = s_dot[b] / (fmaxf(sqrtf(s_yn2[b]), 1e-12f) * pn);
        simsum += s;
        if (b == wave) simw = s;
    }
    const bool  fire  = (simsum * (1.0f / BB)) > 0.85f;
    const float pf    = pos_facil[t];
    const float facil = fire ? fminf(pf * 2.0f, 16.0f) : pf;
    const float g     = fminf(1.0f + kp * (facil - 1.0f) * simw, 8.0f);

    // ---- Phase 5: gated write-out of this wave's row ----
    float* orow = out + ((size_t)wave * TT + t) * DD;
#pragma unroll
    for (int c = 0; c < CHUNKS; ++c) {
        v4f o;
        o.x = xv[c].x * g; o.y = xv[c].y * g;
        o.z = xv[c].z * g; o.w = xv[c].w * g;
        *reinterpret_cast<v4f*>(orow + c * 256 + base) = o;
    }
}

extern "C" void kernel_launch(void* const* d_in, const int* in_sizes, int n_in,
                              void* d_out, int out_size, void* d_ws, size_t ws_size,
                              hipStream_t stream) {
    const float* x          = (const float*)d_in[0];
    const float* log_k_pos  = (const float*)d_in[1];
    const float* pos_buf    = (const float*)d_in[2];
    const float* pos_facil  = (const float*)d_in[3];
    float* out              = (float*)d_out;

    dim3 grid(TT);
    dim3 block(THREADS);
    gelu275_fused<<<grid, block, 0, stream>>>(x, log_k_pos, pos_buf, pos_facil, out);
}